// Round 3
// baseline (460.077 us; speedup 1.0000x reference)
//
#include <hip/hip_runtime.h>

static constexpr int DIN = 128;
static constexpr int HID = 64;

typedef short bf16x8 __attribute__((ext_vector_type(8)));
typedef float f32x4  __attribute__((ext_vector_type(4)));

// bf16 helpers (manual RNE, no header dependence)
__device__ __forceinline__ short f2bf(float f) {
    unsigned u = __float_as_uint(f);
    unsigned r = (u + 0x7fff + ((u >> 16) & 1)) >> 16;
    return (short)r;
}
__device__ __forceinline__ float bf2f(short s) {
    return __uint_as_float(((unsigned)(unsigned short)s) << 16);
}

// ===========================================================================
// CSR build: counting sort of edges by dst (proven code).
// ===========================================================================
__global__ __launch_bounds__(256) void hist_kernel(const int* __restrict__ dst,
                                                   int* __restrict__ cnt, int nE) {
    int i = blockIdx.x * blockDim.x + threadIdx.x;
    if (i < nE) atomicAdd(&cnt[dst[i]], 1);
}

__global__ __launch_bounds__(1024) void scan1_kernel(const int* __restrict__ cnt,
                                                     int* __restrict__ cur,
                                                     int* __restrict__ bsum, int N) {
    __shared__ int s[1024];
    int gid = blockIdx.x * 1024 + threadIdx.x;
    int v = (gid < N) ? cnt[gid] : 0;
    s[threadIdx.x] = v;
    __syncthreads();
    for (int o = 1; o < 1024; o <<= 1) {
        int t = (threadIdx.x >= o) ? s[threadIdx.x - o] : 0;
        __syncthreads();
        s[threadIdx.x] += t;
        __syncthreads();
    }
    if (gid < N) cur[gid] = s[threadIdx.x] - v;
    if (threadIdx.x == 1023) bsum[blockIdx.x] = s[1023];
}

__global__ __launch_bounds__(1024) void scan2_kernel(int* __restrict__ bsum, int nb) {
    __shared__ int s[1024];
    int v = (threadIdx.x < nb) ? bsum[threadIdx.x] : 0;
    s[threadIdx.x] = v;
    __syncthreads();
    for (int o = 1; o < 1024; o <<= 1) {
        int t = (threadIdx.x >= o) ? s[threadIdx.x - o] : 0;
        __syncthreads();
        s[threadIdx.x] += t;
        __syncthreads();
    }
    if (threadIdx.x < nb) bsum[threadIdx.x] = s[threadIdx.x] - v;
}

__global__ __launch_bounds__(1024) void scan3_kernel(int* __restrict__ cur,
                                                     const int* __restrict__ bsum, int N) {
    int gid = blockIdx.x * 1024 + threadIdx.x;
    if (gid < N) cur[gid] += bsum[blockIdx.x];
}

__global__ __launch_bounds__(256) void place_kernel(const int* __restrict__ src,
                                                    const int* __restrict__ dst,
                                                    int* __restrict__ cur,
                                                    int* __restrict__ col, int nE) {
    int i = blockIdx.x * blockDim.x + threadIdx.x;
    if (i < nE) {
        int p = atomicAdd(&cur[dst[i]], 1);
        col[p] = src[i];
    }
}

// ===========================================================================
// pack_w: convert the 4 (Wa|Wb) weight pairs into bf16 hi/lo B-fragment
// order for mfma_f32_16x16x32_bf16. Fragment f = ks*8 + cf covers
// k in [ks*32, ks*32+32), cols [cf*16, cf*16+16). Within a fragment,
// lane l / elem i maps to  k = ks*32 + (l>>4)*8 + i,  col = cf*16 + (l&15).
// Layout: out[f*512 + l*8 + i]  -> proj loads one dwordx4 per (frag, lane).
// The (l>>4, i) -> k map only has to MATCH the A-side load order (it does);
// dot-products over k are permutation-invariant.
// ===========================================================================
struct PackW {
    const float* Wa[4]; const float* Wb[4];
    short* oh[4]; short* ol[4];
    int K[4];
};

__global__ __launch_bounds__(256) void pack_w(PackW p) {
    const int c = blockIdx.y;
    const int K = p.K[c];
    const int t = blockIdx.x * 256 + threadIdx.x;   // t = f*64 + l
    if (t >= K * 16) return;                        // (K/32)*8 frags * 64 lanes
    const int f  = t >> 6, l = t & 63;
    const int ks = f >> 3, cf = f & 7;
    const int col = cf * 16 + (l & 15);
    const int kb  = ks * 32 + ((l >> 4) * 8);
    const float* s = (col < 64) ? (p.Wa[c] + col) : (p.Wb[c] + (col - 64));
    short* oh = p.oh[c] + (size_t)t * 8;
    short* ol = p.ol[c] + (size_t)t * 8;
    #pragma unroll
    for (int i = 0; i < 8; ++i) {
        float v = s[(kb + i) * 64];
        short h = f2bf(v);
        oh[i] = h;
        ol[i] = f2bf(v - bf2f(h));
    }
}

// ===========================================================================
// proj_mfma<K> v3: P[n, 0:128] = x[n, 0:K] @ (Wa|Wb)  via bf16-split MFMA.
//
// Round-2 post-mortem: v2 (32 rows/wave, runtime ks-loop) was latency-bound
// (Occupancy 12%, all pipes <10%, 40.7 us vs 12 us BW floor): 4 HBM loads
// issued per ks iteration, ~900 cy stall each, only 12 waves/CU to hide it.
// v3: (a) 16 rows/wave -> 64-row blocks, 2x the waves (6250 for ng);
//     (b) ks-loop fully unrolled with ALL x-loads hoisted into one batch,
//         so each wave pays HBM latency once, not K/32 times.
//
// In-place safety (Pb == x, layer 2): each wave reads ONLY its own 16 rows
// (all loads issued before any MFMA), epilogue writes those same rows.
// A-frag: lane l = row (l&15), k = ks*32 + (l>>4)*8 + i   (matches pack_w)
// C/D   : col = cf*16 + (l&15), row = lg*4 + q            [HW-verified m89]
// ===========================================================================
template<int K>
__global__ __launch_bounds__(256) void proj_mfma(
    const float* __restrict__ x, const short* __restrict__ WH,
    const short* __restrict__ WL, float* __restrict__ Pa,
    float* __restrict__ Pb, int N)
{
    constexpr int NKS = K / 32;
    const int tid = threadIdx.x;
    const int l   = tid & 63;
    const int w   = tid >> 6;
    const int lr  = l & 15;        // A row / B,D col within fragment
    const int lg  = l >> 4;        // k-group (A) / row-group (D)
    const int r0  = blockIdx.x * 64 + w * 16;
    const int row = r0 + lr;

    // ---- issue ALL x-loads up front (one latency hit, NKS*2 loads in flight)
    float4 u[NKS][2];
    {
        const bool ok = row < N;
        const float* xp = &x[(long long)row * K + lg * 8];
        #pragma unroll
        for (int ks = 0; ks < NKS; ++ks) {
            u[ks][0] = ok ? *(const float4*)(xp + ks * 32)     : make_float4(0.f,0.f,0.f,0.f);
            u[ks][1] = ok ? *(const float4*)(xp + ks * 32 + 4) : make_float4(0.f,0.f,0.f,0.f);
        }
    }

    f32x4 acc[8];
    #pragma unroll
    for (int b = 0; b < 8; ++b) acc[b] = (f32x4){0.f, 0.f, 0.f, 0.f};

    #pragma unroll
    for (int ks = 0; ks < NKS; ++ks) {
        // split this ks-chunk into hi/lo bf16
        bf16x8 ah, al;
        {
            const float vv[8] = {u[ks][0].x, u[ks][0].y, u[ks][0].z, u[ks][0].w,
                                 u[ks][1].x, u[ks][1].y, u[ks][1].z, u[ks][1].w};
            #pragma unroll
            for (int i = 0; i < 8; ++i) {
                short h = f2bf(vv[i]);
                ah[i] = h;
                al[i] = f2bf(vv[i] - bf2f(h));
            }
        }
        const short* wb = WH + (size_t)(ks * 8) * 512 + l * 8;
        const short* lb = WL + (size_t)(ks * 8) * 512 + l * 8;
        #pragma unroll
        for (int cf = 0; cf < 8; ++cf) {
            const bf16x8 bh = *(const bf16x8*)(wb + cf * 512);
            const bf16x8 bl = *(const bf16x8*)(lb + cf * 512);
            acc[cf] = __builtin_amdgcn_mfma_f32_16x16x32_bf16(ah, bh, acc[cf], 0, 0, 0);
            acc[cf] = __builtin_amdgcn_mfma_f32_16x16x32_bf16(ah, bl, acc[cf], 0, 0, 0);
            acc[cf] = __builtin_amdgcn_mfma_f32_16x16x32_bf16(al, bh, acc[cf], 0, 0, 0);
        }
    }

    // ---- epilogue: D row = lg*4 + q, col = cf*16 + lr ----
    #pragma unroll
    for (int q = 0; q < 4; ++q) {
        const int ro = r0 + lg * 4 + q;
        if (ro < N) {
            #pragma unroll
            for (int cf = 0; cf < 8; ++cf) {
                const float v = acc[cf][q];
                if (cf < 4) Pa[(long long)ro * 64 + cf * 16 + lr] = v;
                else        Pb[(long long)ro * 64 + (cf - 4) * 16 + lr] = v;
            }
        }
    }
}

// ===========================================================================
// gather_comb: out[n,:] += mean_{e in CSR(n)} P[col[e],:] + bias[:]
//   (proven code, unchanged)
// ===========================================================================
__global__ __launch_bounds__(256) void gather_comb(
    const float* __restrict__ P, const int* __restrict__ ends,
    const int* __restrict__ col, const float* __restrict__ bias,
    float* __restrict__ out, int N)
{
    const int lane = threadIdx.x & 63;
    const int wid  = (blockIdx.x * 256 + threadIdx.x) >> 6;
    const int n    = wid * 4 + (lane >> 4);
    const int c0   = (lane & 15) << 2;
    if (n >= N) return;

    int e        = (n == 0) ? 0 : ends[n - 1];
    const int e1 = ends[n];
    const int deg = e1 - e;

    float4 acc = make_float4(0.f, 0.f, 0.f, 0.f);
    while (e + 2 <= e1) {
        int s0 = col[e], s1 = col[e + 1];
        const float4 v0 = *(const float4*)&P[(long long)s0 * 64 + c0];
        const float4 v1 = *(const float4*)&P[(long long)s1 * 64 + c0];
        acc.x += v0.x + v1.x; acc.y += v0.y + v1.y;
        acc.z += v0.z + v1.z; acc.w += v0.w + v1.w;
        e += 2;
    }
    if (e < e1) {
        const float4 v0 = *(const float4*)&P[(long long)col[e] * 64 + c0];
        acc.x += v0.x; acc.y += v0.y; acc.z += v0.z; acc.w += v0.w;
    }
    const float inv = (deg > 0) ? 1.0f / (float)deg : 0.0f;
    const float4 b4 = *(const float4*)&bias[c0];
    float4 cur = *(float4*)&out[(long long)n * 64 + c0];
    cur.x += acc.x * inv + b4.x;
    cur.y += acc.y * inv + b4.y;
    cur.z += acc.z * inv + b4.z;
    cur.w += acc.w * inv + b4.w;
    *(float4*)&out[(long long)n * 64 + c0] = cur;
}

extern "C" void kernel_launch(void* const* d_in, const int* in_sizes, int n_in,
                              void* d_out, int out_size, void* d_ws, size_t ws_size,
                              hipStream_t stream) {
    const float* x_d    = (const float*)d_in[0];
    const float* x_g    = (const float*)d_in[1];
    const int* src_dg   = (const int*)d_in[2];
    const int* dst_dg   = (const int*)d_in[3];
    const int* src_gd   = (const int*)d_in[4];
    const int* dst_gd   = (const int*)d_in[5];
    const float* Wl1_dg = (const float*)d_in[6];
    const float* bl1_dg = (const float*)d_in[7];
    const float* Wr1_dg = (const float*)d_in[8];
    const float* Wl1_gd = (const float*)d_in[9];
    const float* bl1_gd = (const float*)d_in[10];
    const float* Wr1_gd = (const float*)d_in[11];
    const float* Wl2_dg = (const float*)d_in[12];
    const float* bl2_dg = (const float*)d_in[13];
    const float* Wr2_dg = (const float*)d_in[14];
    const float* Wl2_gd = (const float*)d_in[15];
    const float* bl2_gd = (const float*)d_in[16];
    const float* Wr2_gd = (const float*)d_in[17];

    const int nd = in_sizes[0] / DIN;   // 50000
    const int ng = in_sizes[1] / DIN;   // 100000
    const int ne = in_sizes[2];         // 600000

    // ---- workspace ----
    float* P_d  = (float*)d_ws;                    // [nd,64]
    float* P_g  = P_d + (size_t)nd * HID;          // [ng,64]
    int* endsG  = (int*)(P_g + (size_t)ng * HID);  // [ng]
    int* endsD  = endsG + ng;                      // [nd]
    int* colG   = endsD + nd;                      // [ne]
    int* colD   = colG + ne;                       // [ne]
    int* cntG   = colD + ne;                       // [ng]
    int* cntD   = cntG + ng;                       // [nd]
    int* bsum   = cntD + nd;                       // [1024]

    // packed bf16 hi/lo weight fragments (16B aligned)
    uintptr_t wp = (uintptr_t)(bsum + 1024);
    wp = (wp + 63) & ~(uintptr_t)63;
    short* wh0 = (short*)wp;        // K=128: 32 frags * 512 = 16384 shorts
    short* wl0 = wh0 + 16384;
    short* wh1 = wl0 + 16384;
    short* wl1 = wh1 + 16384;
    short* wh2 = wl1 + 16384;       // K=64: 16 frags * 512 = 8192
    short* wl2 = wh2 + 8192;
    short* wh3 = wl2 + 8192;
    short* wl3 = wh3 + 8192;

    float* out  = (float*)d_out;
    float* d1r  = out;                             // [nd,64] -> becomes d2
    float* g1r  = out + (size_t)nd * HID;          // [ng,64] -> becomes g2

    const int gE256 = (ne + 255) / 256;
    const int nbG   = (ng + 1023) / 1024;
    const int nbD   = (nd + 1023) / 1024;
    const int gM_g  = (ng + 63) / 64;
    const int gM_d  = (nd + 63) / 64;
    const int gG_g  = (ng + 15) / 16;
    const int gG_d  = (nd + 15) / 16;

    // ---- weight packing (once, tiny) ----
    PackW pw;
    pw.Wa[0] = Wl1_dg; pw.Wb[0] = Wr1_gd; pw.oh[0] = wh0; pw.ol[0] = wl0; pw.K[0] = 128;
    pw.Wa[1] = Wl1_gd; pw.Wb[1] = Wr1_dg; pw.oh[1] = wh1; pw.ol[1] = wl1; pw.K[1] = 128;
    pw.Wa[2] = Wl2_gd; pw.Wb[2] = Wr2_dg; pw.oh[2] = wh2; pw.ol[2] = wl2; pw.K[2] = 64;
    pw.Wa[3] = Wl2_dg; pw.Wb[3] = Wr2_gd; pw.oh[3] = wh3; pw.ol[3] = wl3; pw.K[3] = 64;
    pack_w<<<dim3(8, 4), 256, 0, stream>>>(pw);

    // ---- CSR build, both directions ----
    hipMemsetAsync(cntG, 0, (size_t)(ng + nd) * sizeof(int), stream);

    hist_kernel<<<gE256, 256, 0, stream>>>(dst_dg, cntG, ne);
    scan1_kernel<<<nbG, 1024, 0, stream>>>(cntG, endsG, bsum, ng);
    scan2_kernel<<<1, 1024, 0, stream>>>(bsum, nbG);
    scan3_kernel<<<nbG, 1024, 0, stream>>>(endsG, bsum, ng);
    place_kernel<<<gE256, 256, 0, stream>>>(src_dg, dst_dg, endsG, colG, ne);

    hist_kernel<<<gE256, 256, 0, stream>>>(dst_gd, cntD, ne);
    scan1_kernel<<<nbD, 1024, 0, stream>>>(cntD, endsD, bsum, nd);
    scan2_kernel<<<1, 1024, 0, stream>>>(bsum, nbD);
    scan3_kernel<<<nbD, 1024, 0, stream>>>(endsD, bsum, nd);
    place_kernel<<<gE256, 256, 0, stream>>>(src_gd, dst_gd, endsD, colD, ne);

    // ---- layer 1 ----
    proj_mfma<DIN><<<gM_d, 256, 0, stream>>>(x_d, wh0, wl0, P_d, d1r, nd);
    proj_mfma<DIN><<<gM_g, 256, 0, stream>>>(x_g, wh1, wl1, P_g, g1r, ng);

    gather_comb<<<gG_g, 256, 0, stream>>>(P_d, endsG, colG, bl1_dg, g1r, ng);  // g1
    gather_comb<<<gG_d, 256, 0, stream>>>(P_g, endsD, colD, bl1_gd, d1r, nd);  // d1

    // ---- layer 2 (self-term written in place) ----
    proj_mfma<HID><<<gM_g, 256, 0, stream>>>(g1r, wh2, wl2, P_g, g1r, ng);
    proj_mfma<HID><<<gM_d, 256, 0, stream>>>(d1r, wh3, wl3, P_d, d1r, nd);

    gather_comb<<<gG_d, 256, 0, stream>>>(P_g, endsD, colD, bl2_gd, d1r, nd);  // d2
    gather_comb<<<gG_g, 256, 0, stream>>>(P_d, endsG, colG, bl2_dg, g1r, ng);  // g2
}

// Round 4
// 411.145 us; speedup vs baseline: 1.1190x; 1.1190x over previous
//
#include <hip/hip_runtime.h>

static constexpr int DIN = 128;
static constexpr int HID = 64;

typedef short bf16x8 __attribute__((ext_vector_type(8)));
typedef float f32x4  __attribute__((ext_vector_type(4)));
typedef _Float16 half4 __attribute__((ext_vector_type(4)));

// bf16 helpers (manual RNE, no header dependence)
__device__ __forceinline__ short f2bf(float f) {
    unsigned u = __float_as_uint(f);
    unsigned r = (u + 0x7fff + ((u >> 16) & 1)) >> 16;
    return (short)r;
}
__device__ __forceinline__ float bf2f(short s) {
    return __uint_as_float(((unsigned)(unsigned short)s) << 16);
}

// ===========================================================================
// CSR build (counting sort by dst) — merged both directions per dispatch.
// ===========================================================================
__global__ __launch_bounds__(256) void hist2_kernel(
    const int* __restrict__ dstA, int* __restrict__ cntA,
    const int* __restrict__ dstB, int* __restrict__ cntB, int nE, int gA) {
    const int b = blockIdx.x;
    if (b < gA) {
        int i = b * 256 + threadIdx.x;
        if (i < nE) atomicAdd(&cntA[dstA[i]], 1);
    } else {
        int i = (b - gA) * 256 + threadIdx.x;
        if (i < nE) atomicAdd(&cntB[dstB[i]], 1);
    }
}

__global__ __launch_bounds__(1024) void scan1m_kernel(
    const int* __restrict__ cntA, int* __restrict__ curA, int* __restrict__ bsumA, int NA,
    const int* __restrict__ cntB, int* __restrict__ curB, int* __restrict__ bsumB, int NB,
    int nbA) {
    const int* cnt; int* cur; int* bsum; int N; int bid;
    if (blockIdx.x < nbA) { cnt = cntA; cur = curA; bsum = bsumA; N = NA; bid = blockIdx.x; }
    else                  { cnt = cntB; cur = curB; bsum = bsumB; N = NB; bid = blockIdx.x - nbA; }
    __shared__ int s[1024];
    int gid = bid * 1024 + threadIdx.x;
    int v = (gid < N) ? cnt[gid] : 0;
    s[threadIdx.x] = v;
    __syncthreads();
    for (int o = 1; o < 1024; o <<= 1) {
        int t = (threadIdx.x >= o) ? s[threadIdx.x - o] : 0;
        __syncthreads();
        s[threadIdx.x] += t;
        __syncthreads();
    }
    if (gid < N) cur[gid] = s[threadIdx.x] - v;
    if (threadIdx.x == 1023) bsum[bid] = s[1023];
}

__global__ __launch_bounds__(1024) void scan2m_kernel(
    int* __restrict__ bsumA, int nbA, int* __restrict__ bsumB, int nbB) {
    int* bsum = (blockIdx.x == 0) ? bsumA : bsumB;
    int nb    = (blockIdx.x == 0) ? nbA : nbB;
    __shared__ int s[1024];
    int v = (threadIdx.x < nb) ? bsum[threadIdx.x] : 0;
    s[threadIdx.x] = v;
    __syncthreads();
    for (int o = 1; o < 1024; o <<= 1) {
        int t = (threadIdx.x >= o) ? s[threadIdx.x - o] : 0;
        __syncthreads();
        s[threadIdx.x] += t;
        __syncthreads();
    }
    if (threadIdx.x < nb) bsum[threadIdx.x] = s[threadIdx.x] - v;
}

__global__ __launch_bounds__(1024) void scan3m_kernel(
    int* __restrict__ curA, const int* __restrict__ bsumA, int NA,
    int* __restrict__ curB, const int* __restrict__ bsumB, int NB, int nbA) {
    int* cur; const int* bsum; int N; int bid;
    if (blockIdx.x < nbA) { cur = curA; bsum = bsumA; N = NA; bid = blockIdx.x; }
    else                  { cur = curB; bsum = bsumB; N = NB; bid = blockIdx.x - nbA; }
    int gid = bid * 1024 + threadIdx.x;
    if (gid < N) cur[gid] += bsum[bid];
}

__global__ __launch_bounds__(256) void place2_kernel(
    const int* __restrict__ srcA, const int* __restrict__ dstA,
    int* __restrict__ curA, int* __restrict__ colA,
    const int* __restrict__ srcB, const int* __restrict__ dstB,
    int* __restrict__ curB, int* __restrict__ colB, int nE, int gA) {
    const int b = blockIdx.x;
    if (b < gA) {
        int i = b * 256 + threadIdx.x;
        if (i < nE) { int p = atomicAdd(&curA[dstA[i]], 1); colA[p] = srcA[i]; }
    } else {
        int i = (b - gA) * 256 + threadIdx.x;
        if (i < nE) { int p = atomicAdd(&curB[dstB[i]], 1); colB[p] = srcB[i]; }
    }
}

// ===========================================================================
// pack_w: bf16 hi/lo B-fragments for mfma_f32_16x16x32_bf16 (proven, r2).
// frag f = ks*8+cf: k = ks*32+(l>>4)*8+i, col = cf*16+(l&15);
// layout out[f*512 + l*8 + i]. k-map matches A-side load order.
// ===========================================================================
struct PackW {
    const float* Wa[4]; const float* Wb[4];
    short* oh[4]; short* ol[4];
    int K[4];
};

__global__ __launch_bounds__(256) void pack_w(PackW p) {
    const int c = blockIdx.y;
    const int K = p.K[c];
    const int t = blockIdx.x * 256 + threadIdx.x;   // t = f*64 + l
    if (t >= K * 16) return;
    const int f  = t >> 6, l = t & 63;
    const int ks = f >> 3, cf = f & 7;
    const int col = cf * 16 + (l & 15);
    const int kb  = ks * 32 + ((l >> 4) * 8);
    const float* s = (col < 64) ? (p.Wa[c] + col) : (p.Wb[c] + (col - 64));
    short* oh = p.oh[c] + (size_t)t * 8;
    short* ol = p.ol[c] + (size_t)t * 8;
    #pragma unroll
    for (int i = 0; i < 8; ++i) {
        float v = s[(kb + i) * 64];
        short h = f2bf(v);
        oh[i] = h;
        ol[i] = f2bf(v - bf2f(h));
    }
}

// ===========================================================================
// proj_mfma2<K>: merged dual-projection, two jobs per dispatch (same K).
//   Pa (fp16): message projection x@Wa.  Pb (fp32): self-term x@Wb.
// Structure identical to proven r2/r3 kernel; only Pa stores are fp16 and
// two jobs share one grid (block < blocksA -> job a).
// In-place safety (Pb == x, layer 2): each wave reads only its own 16 rows
// before the epilogue writes them; jobs touch disjoint buffers.
// A-frag: lane l = row (l&15), k = ks*32+(l>>4)*8+i  (matches pack_w)
// C/D   : col = cf*16+(l&15), row = lg*4+q           [HW-verified m89]
// ===========================================================================
struct ProjJob {
    const float* x; const short* WH; const short* WL;
    _Float16* Pa; float* Pb; int N;
};

template<int K>
__global__ __launch_bounds__(256) void proj_mfma2(ProjJob a, ProjJob b, int blocksA)
{
    constexpr int NKS = K / 32;
    const bool isA = (int)blockIdx.x < blocksA;
    const ProjJob j = isA ? a : b;
    const int bid = isA ? blockIdx.x : blockIdx.x - blocksA;

    const int tid = threadIdx.x;
    const int l   = tid & 63;
    const int w   = tid >> 6;
    const int lr  = l & 15;
    const int lg  = l >> 4;
    const int r0  = bid * 64 + w * 16;
    const int row = r0 + lr;

    float4 u[NKS][2];
    {
        const bool ok = row < j.N;
        const float* xp = &j.x[(long long)row * K + lg * 8];
        #pragma unroll
        for (int ks = 0; ks < NKS; ++ks) {
            u[ks][0] = ok ? *(const float4*)(xp + ks * 32)     : make_float4(0.f,0.f,0.f,0.f);
            u[ks][1] = ok ? *(const float4*)(xp + ks * 32 + 4) : make_float4(0.f,0.f,0.f,0.f);
        }
    }

    f32x4 acc[8];
    #pragma unroll
    for (int c = 0; c < 8; ++c) acc[c] = (f32x4){0.f, 0.f, 0.f, 0.f};

    #pragma unroll
    for (int ks = 0; ks < NKS; ++ks) {
        bf16x8 ah, al;
        {
            const float vv[8] = {u[ks][0].x, u[ks][0].y, u[ks][0].z, u[ks][0].w,
                                 u[ks][1].x, u[ks][1].y, u[ks][1].z, u[ks][1].w};
            #pragma unroll
            for (int i = 0; i < 8; ++i) {
                short h = f2bf(vv[i]);
                ah[i] = h;
                al[i] = f2bf(vv[i] - bf2f(h));
            }
        }
        const short* wb = j.WH + (size_t)(ks * 8) * 512 + l * 8;
        const short* lb = j.WL + (size_t)(ks * 8) * 512 + l * 8;
        #pragma unroll
        for (int cf = 0; cf < 8; ++cf) {
            const bf16x8 bh = *(const bf16x8*)(wb + cf * 512);
            const bf16x8 bl = *(const bf16x8*)(lb + cf * 512);
            acc[cf] = __builtin_amdgcn_mfma_f32_16x16x32_bf16(ah, bh, acc[cf], 0, 0, 0);
            acc[cf] = __builtin_amdgcn_mfma_f32_16x16x32_bf16(ah, bl, acc[cf], 0, 0, 0);
            acc[cf] = __builtin_amdgcn_mfma_f32_16x16x32_bf16(al, bh, acc[cf], 0, 0, 0);
        }
    }

    #pragma unroll
    for (int q = 0; q < 4; ++q) {
        const int ro = r0 + lg * 4 + q;
        if (ro < j.N) {
            #pragma unroll
            for (int cf = 0; cf < 8; ++cf) {
                const float v = acc[cf][q];
                if (cf < 4) j.Pa[(long long)ro * 64 + cf * 16 + lr] = (_Float16)v;
                else        j.Pb[(long long)ro * 64 + (cf - 4) * 16 + lr] = v;
            }
        }
    }
}

// ===========================================================================
// gather2: merged mean-aggregate, two jobs per dispatch.
//   out[n,:] += mean_{e in CSR(n)} P[col[e],:] + bias[:]   (P is fp16)
// Wave = 4 nodes, 16 lanes/node; lane covers 4 cols (8 B fp16 load).
// Edge loop unrolled x4 -> 16 independent row-loads in flight per wave.
// ===========================================================================
struct GatherJob {
    const _Float16* P; const int* ends; const int* col;
    const float* bias; float* out; int N;
};

__global__ __launch_bounds__(256) void gather2(GatherJob A, GatherJob B, int blocksA)
{
    const bool isA = (int)blockIdx.x < blocksA;
    const GatherJob g = isA ? A : B;
    const int bid = isA ? blockIdx.x : blockIdx.x - blocksA;

    const int lane = threadIdx.x & 63;
    const int wid  = (bid * 256 + threadIdx.x) >> 6;
    const int n    = wid * 4 + (lane >> 4);
    const int li   = lane & 15;                 // half4 index within row
    if (n >= g.N) return;

    int e        = (n == 0) ? 0 : g.ends[n - 1];
    const int e1 = g.ends[n];
    const int deg = e1 - e;

    float4 acc = make_float4(0.f, 0.f, 0.f, 0.f);
    while (e + 4 <= e1) {
        const int s0 = g.col[e], s1 = g.col[e + 1], s2 = g.col[e + 2], s3 = g.col[e + 3];
        const half4 v0 = *(const half4*)(g.P + (size_t)s0 * 64 + li * 4);
        const half4 v1 = *(const half4*)(g.P + (size_t)s1 * 64 + li * 4);
        const half4 v2 = *(const half4*)(g.P + (size_t)s2 * 64 + li * 4);
        const half4 v3 = *(const half4*)(g.P + (size_t)s3 * 64 + li * 4);
        acc.x += (float)v0[0] + (float)v1[0] + (float)v2[0] + (float)v3[0];
        acc.y += (float)v0[1] + (float)v1[1] + (float)v2[1] + (float)v3[1];
        acc.z += (float)v0[2] + (float)v1[2] + (float)v2[2] + (float)v3[2];
        acc.w += (float)v0[3] + (float)v1[3] + (float)v2[3] + (float)v3[3];
        e += 4;
    }
    while (e < e1) {
        const half4 v0 = *(const half4*)(g.P + (size_t)g.col[e] * 64 + li * 4);
        acc.x += (float)v0[0]; acc.y += (float)v0[1];
        acc.z += (float)v0[2]; acc.w += (float)v0[3];
        ++e;
    }
    const float inv = (deg > 0) ? 1.0f / (float)deg : 0.0f;
    const int c0 = li * 4;
    const float4 b4 = *(const float4*)&g.bias[c0];
    float4 cur = *(float4*)&g.out[(long long)n * 64 + c0];
    cur.x += acc.x * inv + b4.x;
    cur.y += acc.y * inv + b4.y;
    cur.z += acc.z * inv + b4.z;
    cur.w += acc.w * inv + b4.w;
    *(float4*)&g.out[(long long)n * 64 + c0] = cur;
}

extern "C" void kernel_launch(void* const* d_in, const int* in_sizes, int n_in,
                              void* d_out, int out_size, void* d_ws, size_t ws_size,
                              hipStream_t stream) {
    const float* x_d    = (const float*)d_in[0];
    const float* x_g    = (const float*)d_in[1];
    const int* src_dg   = (const int*)d_in[2];
    const int* dst_dg   = (const int*)d_in[3];
    const int* src_gd   = (const int*)d_in[4];
    const int* dst_gd   = (const int*)d_in[5];
    const float* Wl1_dg = (const float*)d_in[6];
    const float* bl1_dg = (const float*)d_in[7];
    const float* Wr1_dg = (const float*)d_in[8];
    const float* Wl1_gd = (const float*)d_in[9];
    const float* bl1_gd = (const float*)d_in[10];
    const float* Wr1_gd = (const float*)d_in[11];
    const float* Wl2_dg = (const float*)d_in[12];
    const float* bl2_dg = (const float*)d_in[13];
    const float* Wr2_dg = (const float*)d_in[14];
    const float* Wl2_gd = (const float*)d_in[15];
    const float* bl2_gd = (const float*)d_in[16];
    const float* Wr2_gd = (const float*)d_in[17];

    const int nd = in_sizes[0] / DIN;   // 50000
    const int ng = in_sizes[1] / DIN;   // 100000
    const int ne = in_sizes[2];         // 600000

    // ---- workspace ----
    _Float16* P_d = (_Float16*)d_ws;                     // [nd,64] fp16
    _Float16* P_g = P_d + (size_t)nd * HID;              // [ng,64] fp16
    int* endsG  = (int*)(P_g + (size_t)ng * HID);        // [ng]  (19.2MB offset, 4B-aligned)
    int* endsD  = endsG + ng;                            // [nd]
    int* colG   = endsD + nd;                            // [ne]
    int* colD   = colG + ne;                             // [ne]
    int* cntG   = colD + ne;                             // [ng]
    int* cntD   = cntG + ng;                             // [nd]
    int* bsumG  = cntD + nd;                             // [1024]
    int* bsumD  = bsumG + 1024;                          // [1024]

    uintptr_t wp = (uintptr_t)(bsumD + 1024);
    wp = (wp + 63) & ~(uintptr_t)63;
    short* wh0 = (short*)wp;        // K=128: 32 frags * 512
    short* wl0 = wh0 + 16384;
    short* wh1 = wl0 + 16384;
    short* wl1 = wh1 + 16384;
    short* wh2 = wl1 + 16384;       // K=64: 16 frags * 512
    short* wl2 = wh2 + 8192;
    short* wh3 = wl2 + 8192;
    short* wl3 = wh3 + 8192;

    float* out  = (float*)d_out;
    float* d1r  = out;                             // [nd,64] -> becomes d2
    float* g1r  = out + (size_t)nd * HID;          // [ng,64] -> becomes g2

    const int gE256 = (ne + 255) / 256;
    const int nbG   = (ng + 1023) / 1024;
    const int nbD   = (nd + 1023) / 1024;
    const int gM_g  = (ng + 63) / 64;
    const int gM_d  = (nd + 63) / 64;
    const int gG_g  = (ng + 15) / 16;
    const int gG_d  = (nd + 15) / 16;

    // ---- weight packing (once, tiny) ----
    PackW pw;
    pw.Wa[0] = Wl1_dg; pw.Wb[0] = Wr1_gd; pw.oh[0] = wh0; pw.ol[0] = wl0; pw.K[0] = 128;
    pw.Wa[1] = Wl1_gd; pw.Wb[1] = Wr1_dg; pw.oh[1] = wh1; pw.ol[1] = wl1; pw.K[1] = 128;
    pw.Wa[2] = Wl2_gd; pw.Wb[2] = Wr2_dg; pw.oh[2] = wh2; pw.ol[2] = wl2; pw.K[2] = 64;
    pw.Wa[3] = Wl2_dg; pw.Wb[3] = Wr2_gd; pw.oh[3] = wh3; pw.ol[3] = wl3; pw.K[3] = 64;
    pack_w<<<dim3(8, 4), 256, 0, stream>>>(pw);

    // ---- CSR build, both directions merged per stage ----
    hipMemsetAsync(cntG, 0, (size_t)(ng + nd) * sizeof(int), stream);

    hist2_kernel<<<2 * gE256, 256, 0, stream>>>(dst_dg, cntG, dst_gd, cntD, ne, gE256);
    scan1m_kernel<<<nbG + nbD, 1024, 0, stream>>>(cntG, endsG, bsumG, ng,
                                                  cntD, endsD, bsumD, nd, nbG);
    scan2m_kernel<<<2, 1024, 0, stream>>>(bsumG, nbG, bsumD, nbD);
    scan3m_kernel<<<nbG + nbD, 1024, 0, stream>>>(endsG, bsumG, ng, endsD, bsumD, nd, nbG);
    place2_kernel<<<2 * gE256, 256, 0, stream>>>(src_dg, dst_dg, endsG, colG,
                                                 src_gd, dst_gd, endsD, colD, ne, gE256);

    // ---- layer 1: merged dual projections (K=128) ----
    ProjJob p1a = { x_d, wh0, wl0, P_d, d1r, nd };   // msg for genes + self of d1
    ProjJob p1b = { x_g, wh1, wl1, P_g, g1r, ng };   // msg for diseases + self of g1
    proj_mfma2<DIN><<<gM_d + gM_g, 256, 0, stream>>>(p1a, p1b, gM_d);

    GatherJob ga1 = { P_d, endsG, colG, bl1_dg, g1r, ng };  // g1
    GatherJob gb1 = { P_g, endsD, colD, bl1_gd, d1r, nd };  // d1
    gather2<<<gG_g + gG_d, 256, 0, stream>>>(ga1, gb1, gG_g);

    // ---- layer 2: merged dual projections (K=64), self-term in place ----
    ProjJob p2a = { g1r, wh2, wl2, P_g, g1r, ng };   // msg for d2 + self of g2
    ProjJob p2b = { d1r, wh3, wl3, P_d, d1r, nd };   // msg for g2 + self of d2
    proj_mfma2<HID><<<gM_g + gM_d, 256, 0, stream>>>(p2a, p2b, gM_g);

    GatherJob ga2 = { P_g, endsD, colD, bl2_gd, d1r, nd };  // d2
    GatherJob gb2 = { P_d, endsG, colG, bl2_dg, g1r, ng };  // g2
    gather2<<<gG_d + gG_g, 256, 0, stream>>>(ga2, gb2, gG_d);
}